// Round 1
// baseline (291.350 us; speedup 1.0000x reference)
//
#include <hip/hip_runtime.h>

// Problem constants (from reference): B=64, NIN=512, H1=1024, H2=1024,
// NOUT=512, COND=64, FC=1.
#define BB   64
#define NIN  512
#define H1D  1024
#define H2D  1024
#define NOUTD 512
#define CONDD 64

// ---------------------------------------------------------------------------
// Prep kernel: computes all six small GEMMs  out_t[n,b] = sum_k u[b,k]*w[n,k]
// + bias[n]  (transposed layout, feature-major / batch-minor), plus the
// transpose of x into x_t[i,b].  All independent of the layer chain.
//   blocks 0..1279   : GEMM rows, 4 rows/block (one row per wave)
//   blocks 1280..1287: x transpose tiles (64 x 64)
// ---------------------------------------------------------------------------
__global__ __launch_bounds__(256) void prep_kernel(
    const float* __restrict__ x,  const float* __restrict__ u,
    const float* __restrict__ a0w, const float* __restrict__ a0b,
    const float* __restrict__ b0w, const float* __restrict__ b0b,
    const float* __restrict__ a1w, const float* __restrict__ a1b,
    const float* __restrict__ b1w, const float* __restrict__ b1b,
    const float* __restrict__ a2w, const float* __restrict__ a2b,
    const float* __restrict__ b2w, const float* __restrict__ b2b,
    float* __restrict__ xt,
    float* __restrict__ A0, float* __restrict__ C0,
    float* __restrict__ A1, float* __restrict__ C1,
    float* __restrict__ A2, float* __restrict__ C2)
{
    __shared__ float lds[64 * 65];   // +1 pad: conflict-free transposed access
    const int tid = threadIdx.x;
    const int bid = blockIdx.x;

    if (bid < 1280) {
        const float* w; const float* bias; float* out; int base;
        if      (bid <  128) { w = a0w; bias = a0b; out = A0; base = bid         * 4; }
        else if (bid <  384) { w = b0w; bias = b0b; out = C0; base = (bid -  128) * 4; }
        else if (bid <  640) { w = a1w; bias = a1b; out = A1; base = (bid -  384) * 4; }
        else if (bid <  896) { w = b1w; bias = b1b; out = C1; base = (bid -  640) * 4; }
        else if (bid < 1152) { w = a2w; bias = a2b; out = A2; base = (bid -  896) * 4; }
        else                 { w = b2w; bias = b2b; out = C2; base = (bid - 1152) * 4; }

        // stage u transposed into LDS: lds[k*65 + b] = u[b*64 + k]
        for (int e = tid; e < BB * CONDD; e += 256)
            lds[(e & 63) * 65 + (e >> 6)] = u[e];
        __syncthreads();

        const int b = tid & 63;
        const int j = __builtin_amdgcn_readfirstlane(tid >> 6);  // wave-uniform
        const int row = base + j;
        const float* __restrict__ wr = w + row * CONDD;
        float acc = bias[row];
        #pragma unroll
        for (int k = 0; k < CONDD; ++k)
            acc = fmaf(wr[k], lds[k * 65 + b], acc);
        out[row * 64 + b] = acc;
    } else {
        // transpose one 64(b) x 64(i) tile of x into xt
        const int i0 = (bid - 1280) * 64;
        for (int e = tid; e < 64 * 64; e += 256) {
            int r = e >> 6, c = e & 63;                // r=b, c=i offset
            lds[c * 65 + r] = x[r * NIN + i0 + c];     // coalesced read
        }
        __syncthreads();
        for (int e = tid; e < 64 * 64; e += 256) {
            int r = e >> 6, c = e & 63;                // r=i offset, c=b
            xt[(i0 + r) * 64 + c] = lds[r * 65 + c];   // coalesced write
        }
    }
}

// ---------------------------------------------------------------------------
// Gated masked matvec (the ConditionedMaskedLinear core, FC=1):
//   out[b,o] = sum_i sigmoid(At[i,b]*Ct[o,b]) * (M[o,i]*W[o,i]) * xt[i,b]
// One block per o; lane = b; 4 waves split i into contiguous quarters.
// i is wave-uniform -> M/W loads are scalar and the mask-zero skip is a
// uniform branch (saves exp + both vector loads on ~50% of iterations).
// ---------------------------------------------------------------------------
template<int I, bool FINAL>
__global__ __launch_bounds__(256) void gated_kernel(
    const float* __restrict__ xt, const float* __restrict__ At,
    const float* __restrict__ Ct, const float* __restrict__ M,
    const float* __restrict__ W,  float* __restrict__ out, int O)
{
    const int tid = threadIdx.x;
    const int b = tid & 63;
    const int j = __builtin_amdgcn_readfirstlane(tid >> 6);  // 0..3, uniform
    const int o = blockIdx.x;

    const float c = Ct[o * 64 + b];
    const float* __restrict__ Wrow = W + (size_t)o * I;
    const float* __restrict__ Mrow = M + (size_t)o * I;

    float acc = 0.f;
    const int i_beg = j * (I / 4);
    const int i_end = i_beg + (I / 4);
    #pragma unroll 4
    for (int i = i_beg; i < i_end; ++i) {
        float mw = Mrow[i] * Wrow[i];          // wave-uniform (scalar pipe)
        if (mw != 0.f) {                       // uniform branch
            float z = At[i * 64 + b] * c;
            float e = __expf(-z);              // v_exp_f32
            float s = __builtin_amdgcn_rcpf(1.f + e);  // v_rcp_f32
            acc = fmaf(s * mw, xt[i * 64 + b], acc);
        }
    }

    __shared__ float red[256];
    red[tid] = acc;
    __syncthreads();
    if (tid < 64) {
        float v = red[tid] + red[tid + 64] + red[tid + 128] + red[tid + 192];
        if (FINAL) out[tid * O + o] = v;       // untransposed (B, NOUT) store
        else       out[o * 64 + tid] = v;      // keep transposed for next layer
    }
}

// ---------------------------------------------------------------------------
extern "C" void kernel_launch(void* const* d_in, const int* in_sizes, int n_in,
                              void* d_out, int out_size, void* d_ws, size_t ws_size,
                              hipStream_t stream) {
    (void)in_sizes; (void)n_in; (void)out_size; (void)ws_size;
    const float* x   = (const float*)d_in[0];
    const float* u   = (const float*)d_in[1];
    const float* m0  = (const float*)d_in[2];
    const float* m1  = (const float*)d_in[3];
    const float* m2  = (const float*)d_in[4];
    const float* W0  = (const float*)d_in[5];
    const float* W1  = (const float*)d_in[6];
    const float* W2  = (const float*)d_in[7];
    const float* a0w = (const float*)d_in[8];  const float* a0b = (const float*)d_in[9];
    const float* b0w = (const float*)d_in[10]; const float* b0b = (const float*)d_in[11];
    const float* a1w = (const float*)d_in[12]; const float* a1b = (const float*)d_in[13];
    const float* b1w = (const float*)d_in[14]; const float* b1b = (const float*)d_in[15];
    const float* a2w = (const float*)d_in[16]; const float* a2b = (const float*)d_in[17];
    const float* b2w = (const float*)d_in[18]; const float* b2b = (const float*)d_in[19];

    float* ws = (float*)d_ws;
    float* xt = ws;               // 512*64
    float* A0 = ws + 32768;       // 512*64
    float* C0 = ws + 65536;       // 1024*64
    float* A1 = ws + 131072;      // 1024*64
    float* C1 = ws + 196608;      // 1024*64
    float* A2 = ws + 262144;      // 1024*64
    float* C2 = ws + 327680;      // 512*64
    float* h1 = ws + 360448;      // 1024*64
    float* h2 = ws + 425984;      // 1024*64
    float* out = (float*)d_out;

    prep_kernel<<<1288, 256, 0, stream>>>(x, u,
        a0w, a0b, b0w, b0b, a1w, a1b, b1w, b1b, a2w, a2b, b2w, b2b,
        xt, A0, C0, A1, C1, A2, C2);

    gated_kernel<NIN,  false><<<H1D,   256, 0, stream>>>(xt, A0, C0, m0, W0, h1, H1D);
    gated_kernel<H1D,  false><<<H2D,   256, 0, stream>>>(h1, A1, C1, m1, W1, h2, H2D);
    gated_kernel<H2D,  true ><<<NOUTD, 256, 0, stream>>>(h2, A2, C2, m2, W2, out, NOUTD);
}

// Round 2
// 274.665 us; speedup vs baseline: 1.0607x; 1.0607x over previous
//
#include <hip/hip_runtime.h>

// Problem constants: B=64, NIN=512, H1=1024, H2=1024, NOUT=512, COND=64, FC=1.
#define BB   64
#define NIN  512
#define H1D  1024
#define H2D  1024
#define NOUTD 512
#define CONDD 64

__device__ __forceinline__ float fsig(float z) {
    float e = __expf(-z);                    // v_mul + v_exp_f32
    return __builtin_amdgcn_rcpf(1.f + e);   // v_add + v_rcp_f32
}

// ---------------------------------------------------------------------------
// Prep kernel:
//   blocks 0..1279   : six cond GEMMs  out_t[n,b] = sum_k u[b,k]*w[n,k]+bias[n]
//   blocks 1280..1287: x transpose tiles (64 x 64) -> xt[i,b]
//   blocks 1288..1447: zero h1/h2/h3 (atomic accumulators), contiguous region
// ---------------------------------------------------------------------------
__global__ __launch_bounds__(256) void prep_kernel(
    const float* __restrict__ x,  const float* __restrict__ u,
    const float* __restrict__ a0w, const float* __restrict__ a0b,
    const float* __restrict__ b0w, const float* __restrict__ b0b,
    const float* __restrict__ a1w, const float* __restrict__ a1b,
    const float* __restrict__ b1w, const float* __restrict__ b1b,
    const float* __restrict__ a2w, const float* __restrict__ a2b,
    const float* __restrict__ b2w, const float* __restrict__ b2b,
    float* __restrict__ xt,
    float* __restrict__ A0, float* __restrict__ C0,
    float* __restrict__ A1, float* __restrict__ C1,
    float* __restrict__ A2, float* __restrict__ C2,
    float* __restrict__ zero_base /* h1..h3, 163840 floats */)
{
    __shared__ float lds[64 * 65];
    const int tid = threadIdx.x;
    const int bid = blockIdx.x;

    if (bid < 1280) {
        const float* w; const float* bias; float* out; int base;
        if      (bid <  128) { w = a0w; bias = a0b; out = A0; base = bid          * 4; }
        else if (bid <  384) { w = b0w; bias = b0b; out = C0; base = (bid -  128) * 4; }
        else if (bid <  640) { w = a1w; bias = a1b; out = A1; base = (bid -  384) * 4; }
        else if (bid <  896) { w = b1w; bias = b1b; out = C1; base = (bid -  640) * 4; }
        else if (bid < 1152) { w = a2w; bias = a2b; out = A2; base = (bid -  896) * 4; }
        else                 { w = b2w; bias = b2b; out = C2; base = (bid - 1152) * 4; }

        for (int e = tid; e < BB * CONDD; e += 256)
            lds[(e & 63) * 65 + (e >> 6)] = u[e];
        __syncthreads();

        const int b = tid & 63;
        const int j = __builtin_amdgcn_readfirstlane(tid >> 6);
        const int row = base + j;
        const float* __restrict__ wr = w + row * CONDD;
        float acc = bias[row];
        #pragma unroll
        for (int k = 0; k < CONDD; ++k)
            acc = fmaf(wr[k], lds[k * 65 + b], acc);
        out[row * 64 + b] = acc;
    } else if (bid < 1288) {
        const int i0 = (bid - 1280) * 64;
        for (int e = tid; e < 64 * 64; e += 256) {
            int r = e >> 6, c = e & 63;                // r=b, c=i offset
            lds[c * 65 + r] = x[r * NIN + i0 + c];
        }
        __syncthreads();
        for (int e = tid; e < 64 * 64; e += 256) {
            int r = e >> 6, c = e & 63;                // r=i offset, c=b
            xt[(i0 + r) * 64 + c] = lds[r * 65 + c];
        }
    } else {
        // zero 163840 floats = 40960 float4 across 160 blocks
        const int idx = (bid - 1288) * 256 + tid;
        ((float4*)zero_base)[idx] = make_float4(0.f, 0.f, 0.f, 0.f);
    }
}

// ---------------------------------------------------------------------------
// Register-tiled gated masked matvec:
//   out[o,b] += sum_{i in chunk} sigmoid(At[i,b]*Ct[o,b]) * M[o,i]*W[o,i] * xt[i,b]
// Each wave: lane=b, holds IC=16 (At,xt) values in registers, loops over OG
// o's, one coalesced HW float atomic per (wave,o). M/W rows are wave-uniform
// scalar loads; mask-zero skip is a uniform branch (saves exp+rcp).
// ---------------------------------------------------------------------------
template<int I, int O, int OG>
__global__ __launch_bounds__(256) void gated_kernel(
    const float* __restrict__ xt, const float* __restrict__ At,
    const float* __restrict__ Ct, const float* __restrict__ M,
    const float* __restrict__ W,  float* __restrict__ out)
{
    constexpr int IC  = 16;
    constexpr int NCH = I / IC;               // i-chunks (power of 2)
    const int tid = threadIdx.x;
    const int b   = tid & 63;
    const int wid = __builtin_amdgcn_readfirstlane(tid >> 6);
    const int gid = blockIdx.x * 4 + wid;     // global wave id
    const int chunk = gid % NCH;
    const int og    = gid / NCH;
    const int i0 = chunk * IC;

    float av[IC], xv[IC];
    #pragma unroll
    for (int ii = 0; ii < IC; ++ii) {
        av[ii] = At[(i0 + ii) * 64 + b];
        xv[ii] = xt[(i0 + ii) * 64 + b];
    }

    for (int oo = 0; oo < OG; ++oo) {
        const int o = og * OG + oo;
        const float cc = Ct[o * 64 + b];
        const float* __restrict__ mrow = M + (size_t)o * I + i0;
        const float* __restrict__ wrow = W + (size_t)o * I + i0;
        float acc0 = 0.f, acc1 = 0.f;
        #pragma unroll
        for (int ii = 0; ii < IC; ii += 2) {
            const float mw0 = mrow[ii]     * wrow[ii];
            const float mw1 = mrow[ii + 1] * wrow[ii + 1];
            if (mw0 != 0.f)
                acc0 = fmaf(mw0 * xv[ii],     fsig(av[ii]     * cc), acc0);
            if (mw1 != 0.f)
                acc1 = fmaf(mw1 * xv[ii + 1], fsig(av[ii + 1] * cc), acc1);
        }
        __hip_atomic_fetch_add(out + o * 64 + b, acc0 + acc1,
                               __ATOMIC_RELAXED, __HIP_MEMORY_SCOPE_AGENT);
    }
}

// ---------------------------------------------------------------------------
// Final transpose: h3[o,b] -> out[b, NOUT] (coalesced both ways)
// ---------------------------------------------------------------------------
__global__ __launch_bounds__(256) void finalize_kernel(
    const float* __restrict__ h3, float* __restrict__ out)
{
    __shared__ float lds[64 * 65];
    const int o0 = blockIdx.x * 64;
    const int tid = threadIdx.x;
    for (int e = tid; e < 64 * 64; e += 256) {
        int r = e >> 6, c = e & 63;            // r = o offset, c = b
        lds[c * 65 + r] = h3[(o0 + r) * 64 + c];
    }
    __syncthreads();
    for (int e = tid; e < 64 * 64; e += 256) {
        int r = e >> 6, c = e & 63;            // r = b, c = o offset
        out[r * NOUTD + o0 + c] = lds[r * 65 + c];
    }
}

// ---------------------------------------------------------------------------
extern "C" void kernel_launch(void* const* d_in, const int* in_sizes, int n_in,
                              void* d_out, int out_size, void* d_ws, size_t ws_size,
                              hipStream_t stream) {
    (void)in_sizes; (void)n_in; (void)out_size; (void)ws_size;
    const float* x   = (const float*)d_in[0];
    const float* u   = (const float*)d_in[1];
    const float* m0  = (const float*)d_in[2];
    const float* m1  = (const float*)d_in[3];
    const float* m2  = (const float*)d_in[4];
    const float* W0  = (const float*)d_in[5];
    const float* W1  = (const float*)d_in[6];
    const float* W2  = (const float*)d_in[7];
    const float* a0w = (const float*)d_in[8];  const float* a0b = (const float*)d_in[9];
    const float* b0w = (const float*)d_in[10]; const float* b0b = (const float*)d_in[11];
    const float* a1w = (const float*)d_in[12]; const float* a1b = (const float*)d_in[13];
    const float* b1w = (const float*)d_in[14]; const float* b1b = (const float*)d_in[15];
    const float* a2w = (const float*)d_in[16]; const float* a2b = (const float*)d_in[17];
    const float* b2w = (const float*)d_in[18]; const float* b2b = (const float*)d_in[19];

    float* ws = (float*)d_ws;
    float* xt = ws;               // 512*64   = 32768
    float* A0 = ws + 32768;       // 512*64
    float* C0 = ws + 65536;       // 1024*64
    float* A1 = ws + 131072;      // 1024*64
    float* C1 = ws + 196608;      // 1024*64
    float* A2 = ws + 262144;      // 1024*64
    float* C2 = ws + 327680;      // 512*64
    float* h1 = ws + 360448;      // 1024*64  (zeroed)
    float* h2 = ws + 425984;      // 1024*64  (zeroed)
    float* h3 = ws + 491520;      // 512*64   (zeroed)
    float* out = (float*)d_out;

    prep_kernel<<<1448, 256, 0, stream>>>(x, u,
        a0w, a0b, b0w, b0b, a1w, a1b, b1w, b1b, a2w, a2b, b2w, b2b,
        xt, A0, C0, A1, C1, A2, C2, h1);

    // waves = (I/16) * (O/OG) = 4096 per layer -> 1024 blocks of 4 waves
    gated_kernel<NIN,  H1D,   8><<<1024, 256, 0, stream>>>(xt, A0, C0, m0, W0, h1);
    gated_kernel<H1D,  H2D,  16><<<1024, 256, 0, stream>>>(h1, A1, C1, m1, W1, h2);
    gated_kernel<H1D,  NOUTD, 8><<<1024, 256, 0, stream>>>(h2, A2, C2, m2, W2, h3);

    finalize_kernel<<<NOUTD / 64, 256, 0, stream>>>(h3, out);
}

// Round 3
// 166.513 us; speedup vs baseline: 1.7497x; 1.6495x over previous
//
#include <hip/hip_runtime.h>

// Problem constants: B=64, NIN=512, H1=1024, H2=1024, NOUT=512, COND=64, FC=1.
#define BB    64
#define NIN   512
#define H1D   1024
#define H2D   1024
#define NOUTD 512
#define CONDD 64

__device__ __forceinline__ float fsig(float z) {
    float e = __expf(-z);                    // v_mul + v_exp_f32; overflow->inf is fine
    return __builtin_amdgcn_rcpf(1.f + e);   // rcp(inf)=0 -> sigma=0, never NaN
}

// ---------------------------------------------------------------------------
// Prep kernel (one launch, block ranges):
//   [0,1280)      six cond GEMMs  out[n,b] = sum_k u[b,k]*w[n,k] + bias[n]
//                 A-outputs go to AX[n][b].x (stride-2), C-outputs flat.
//   [1280,1288)   x transpose tiles -> AX0[i][b].y
//   [1288,3336)   MW = mask .* W elementwise (float4), 3 layers concatenated
// ---------------------------------------------------------------------------
__global__ __launch_bounds__(256) void prep_kernel(
    const float* __restrict__ x,  const float* __restrict__ u,
    const float* __restrict__ m0, const float* __restrict__ W0,
    const float* __restrict__ m1, const float* __restrict__ W1,
    const float* __restrict__ m2, const float* __restrict__ W2,
    const float* __restrict__ a0w, const float* __restrict__ a0b,
    const float* __restrict__ b0w, const float* __restrict__ b0b,
    const float* __restrict__ a1w, const float* __restrict__ a1b,
    const float* __restrict__ b1w, const float* __restrict__ b1b,
    const float* __restrict__ a2w, const float* __restrict__ a2b,
    const float* __restrict__ b2w, const float* __restrict__ b2b,
    float* __restrict__ AX0, float* __restrict__ AX1, float* __restrict__ AX2,
    float* __restrict__ C0t, float* __restrict__ C1t, float* __restrict__ C2t,
    float* __restrict__ MW0, float* __restrict__ MW1, float* __restrict__ MW2)
{
    __shared__ float lds[64 * 65];
    const int tid = threadIdx.x;
    const int bid = blockIdx.x;

    if (bid < 1280) {
        // six GEMMs, 4 rows/block (one row per wave)
        const float* w; const float* bias; float* out; int base; int stride;
        if      (bid <  128) { w = a0w; bias = a0b; out = AX0;  base = bid          * 4; stride = 2; }
        else if (bid <  384) { w = b0w; bias = b0b; out = C0t;  base = (bid -  128) * 4; stride = 1; }
        else if (bid <  640) { w = a1w; bias = a1b; out = AX1;  base = (bid -  384) * 4; stride = 2; }
        else if (bid <  896) { w = b1w; bias = b1b; out = C1t;  base = (bid -  640) * 4; stride = 1; }
        else if (bid < 1152) { w = a2w; bias = a2b; out = AX2;  base = (bid -  896) * 4; stride = 2; }
        else                 { w = b2w; bias = b2b; out = C2t;  base = (bid - 1152) * 4; stride = 1; }

        for (int e = tid; e < BB * CONDD; e += 256)
            lds[(e & 63) * 65 + (e >> 6)] = u[e];
        __syncthreads();

        const int b = tid & 63;
        const int j = __builtin_amdgcn_readfirstlane(tid >> 6);
        const int row = base + j;
        const float* __restrict__ wr = w + row * CONDD;
        float acc = bias[row];
        #pragma unroll
        for (int k = 0; k < CONDD; ++k)
            acc = fmaf(wr[k], lds[k * 65 + b], acc);
        out[(row * 64 + b) * stride] = acc;
    } else if (bid < 1288) {
        // transpose one 64(b) x 64(i) tile of x into AX0 .y slots
        const int i0 = (bid - 1280) * 64;
        for (int e = tid; e < 64 * 64; e += 256) {
            int r = e >> 6, c = e & 63;                // r=b, c=i offset
            lds[c * 65 + r] = x[r * NIN + i0 + c];
        }
        __syncthreads();
        for (int e = tid; e < 64 * 64; e += 256) {
            int r = e >> 6, c = e & 63;                // r=i offset, c=b
            AX0[((i0 + r) * 64 + c) * 2 + 1] = lds[r * 65 + c];
        }
    } else {
        // MW = m .* W, float4 granularity. Layer sizes (float4 units):
        //   MW0: 131072, MW1: 262144, MW2: 131072  -> total 524288 = 2048 blocks
        const int e = (bid - 1288) * 256 + tid;        // float4 index
        const float4* ms; const float4* wsrc; float4* dst; int off;
        if      (e < 131072)  { ms = (const float4*)m0; wsrc = (const float4*)W0; dst = (float4*)MW0; off = e; }
        else if (e < 393216)  { ms = (const float4*)m1; wsrc = (const float4*)W1; dst = (float4*)MW1; off = e - 131072; }
        else                  { ms = (const float4*)m2; wsrc = (const float4*)W2; dst = (float4*)MW2; off = e - 393216; }
        float4 a = ms[off], b4 = wsrc[off];
        dst[off] = make_float4(a.x * b4.x, a.y * b4.y, a.z * b4.z, a.w * b4.w);
    }
}

// ---------------------------------------------------------------------------
// Branchless gated masked matvec:
//   out[o,b] = sum_i sigmoid(AX[i][b].x * Ct[o,b]) * MW[o,i] * AX[i][b].y
// Block: 2 o's (opair), 4 waves split the block's i-extent into 4 chunks.
// NSPLIT=2 splits I across two block sets writing h-partials (no atomics).
// MW is wave-uniform -> s_load; loop is dense -> deep pipelining.
// ---------------------------------------------------------------------------
template<int I_TOTAL, int NSPLIT, int OPAIRS, bool ILV>
__global__ __launch_bounds__(256) void gated_kernel(
    const float2* __restrict__ AX, const float* __restrict__ Ct,
    const float*  __restrict__ MW, float* __restrict__ out0,
    float* __restrict__ out1)
{
    constexpr int ICHUNK = I_TOTAL / NSPLIT;   // per-block i extent
    constexpr int ICW    = ICHUNK / 4;         // per-wave i extent
    const int tid  = threadIdx.x;
    const int b    = tid & 63;
    const int wid  = tid >> 6;
    const int opair = blockIdx.x % OPAIRS;
    const int ihalf = blockIdx.x / OPAIRS;
    const int o0    = opair * 2;
    const int ibase = ihalf * ICHUNK + wid * ICW;

    const float cc0 = Ct[o0 * 64 + b];
    const float cc1 = Ct[(o0 + 1) * 64 + b];
    const float* __restrict__ mw0p = MW + (size_t)o0       * I_TOTAL + ibase;
    const float* __restrict__ mw1p = MW + (size_t)(o0 + 1) * I_TOTAL + ibase;
    const float2* __restrict__ axp = AX + (size_t)ibase * 64 + b;

    float acc0 = 0.f, acc1 = 0.f;
    #pragma unroll 8
    for (int ii = 0; ii < ICW; ++ii) {
        const float2 ax = axp[ii * 64];
        const float mw0 = mw0p[ii];            // wave-uniform s_load
        const float mw1 = mw1p[ii];
        acc0 = fmaf(fsig(ax.x * cc0), mw0 * ax.y, acc0);
        acc1 = fmaf(fsig(ax.x * cc1), mw1 * ax.y, acc1);
    }

    __shared__ float red[4][2][64];
    red[wid][0][b] = acc0;
    red[wid][1][b] = acc1;
    __syncthreads();
    if (tid < 128) {
        const int oo = tid >> 6, bb = tid & 63;
        float v = red[0][oo][bb] + red[1][oo][bb] + red[2][oo][bb] + red[3][oo][bb];
        float* outp = ihalf ? out1 : out0;
        if (ILV) outp[((o0 + oo) * 64 + bb) * 2 + 1] = v;   // next layer's AX .y
        else     outp[(o0 + oo) * 64 + bb] = v;             // flat partial
    }
}

// ---------------------------------------------------------------------------
// Final: out[b, o] = h3a[o,b] + h3b[o,b], transposed store (coalesced).
// ---------------------------------------------------------------------------
__global__ __launch_bounds__(256) void finalize_kernel(
    const float* __restrict__ h3a, const float* __restrict__ h3b,
    float* __restrict__ out)
{
    __shared__ float lds[64 * 65];
    const int o0 = blockIdx.x * 64;
    const int tid = threadIdx.x;
    for (int e = tid; e < 64 * 64; e += 256) {
        int r = e >> 6, c = e & 63;            // r = o offset, c = b
        lds[c * 65 + r] = h3a[(o0 + r) * 64 + c] + h3b[(o0 + r) * 64 + c];
    }
    __syncthreads();
    for (int e = tid; e < 64 * 64; e += 256) {
        int r = e >> 6, c = e & 63;            // r = b, c = o offset
        out[r * NOUTD + o0 + c] = lds[r * 65 + c];
    }
}

// ---------------------------------------------------------------------------
extern "C" void kernel_launch(void* const* d_in, const int* in_sizes, int n_in,
                              void* d_out, int out_size, void* d_ws, size_t ws_size,
                              hipStream_t stream) {
    (void)in_sizes; (void)n_in; (void)out_size; (void)ws_size;
    const float* x   = (const float*)d_in[0];
    const float* u   = (const float*)d_in[1];
    const float* m0  = (const float*)d_in[2];
    const float* m1  = (const float*)d_in[3];
    const float* m2  = (const float*)d_in[4];
    const float* W0  = (const float*)d_in[5];
    const float* W1  = (const float*)d_in[6];
    const float* W2  = (const float*)d_in[7];
    const float* a0w = (const float*)d_in[8];  const float* a0b = (const float*)d_in[9];
    const float* b0w = (const float*)d_in[10]; const float* b0b = (const float*)d_in[11];
    const float* a1w = (const float*)d_in[12]; const float* a1b = (const float*)d_in[13];
    const float* b1w = (const float*)d_in[14]; const float* b1b = (const float*)d_in[15];
    const float* a2w = (const float*)d_in[16]; const float* a2b = (const float*)d_in[17];
    const float* b2w = (const float*)d_in[18]; const float* b2b = (const float*)d_in[19];

    float* ws = (float*)d_ws;                  // offsets in floats
    float* AX0 = ws;                           // float2[512*64]   = 65536
    float* AX1 = ws + 65536;                   // float2[1024*64]  = 131072
    float* AX2 = ws + 196608;                  // float2[1024*64]  = 131072
    float* C0t = ws + 327680;                  // 1024*64 = 65536
    float* C1t = ws + 393216;                  // 1024*64 = 65536
    float* C2t = ws + 458752;                  // 512*64  = 32768
    float* MW0 = ws + 491520;                  // 1024*512  = 524288
    float* MW1 = ws + 1015808;                 // 1024*1024 = 1048576
    float* MW2 = ws + 2064384;                 // 512*1024  = 524288
    float* h3a = ws + 2588672;                 // 512*64 = 32768
    float* h3b = ws + 2621440;                 // 512*64 = 32768
    float* out = (float*)d_out;

    prep_kernel<<<3336, 256, 0, stream>>>(x, u, m0, W0, m1, W1, m2, W2,
        a0w, a0b, b0w, b0b, a1w, a1b, b1w, b1b, a2w, a2b, b2w, b2b,
        AX0, AX1, AX2, C0t, C1t, C2t, MW0, MW1, MW2);

    // L1: I=512,  O=1024 -> 512 blocks; writes AX1 .y
    gated_kernel<512, 1, 512, true><<<512, 256, 0, stream>>>(
        (const float2*)AX0, C0t, MW0, AX1, nullptr);
    // L2: I=1024, O=1024 -> 512 blocks; writes AX2 .y
    gated_kernel<1024, 1, 512, true><<<512, 256, 0, stream>>>(
        (const float2*)AX1, C1t, MW1, AX2, nullptr);
    // L3: I=1024 split 2x, O=512 -> 512 blocks; writes h3a/h3b partials
    gated_kernel<1024, 2, 256, false><<<512, 256, 0, stream>>>(
        (const float2*)AX2, C2t, MW2, h3a, h3b);

    finalize_kernel<<<NOUTD / 64, 256, 0, stream>>>(h3a, h3b, out);
}

// Round 4
// 152.094 us; speedup vs baseline: 1.9156x; 1.0948x over previous
//
#include <hip/hip_runtime.h>

// Problem constants: B=64, NIN=512, H1=1024, H2=1024, NOUT=512, COND=64, FC=1.
#define BB    64
#define NIN   512
#define H1D   1024
#define H2D   1024
#define NOUTD 512
#define CONDD 64
#define L2E   1.4426950408889634f   // log2(e)

// ---------------------------------------------------------------------------
// Prep kernel:
//   blocks [0,320): six cond GEMMs, 16 rows/block (4 rows/wave), rows
//                   concatenated [A0|C0|A1|C1|A2|C2] = 5120 rows.
//                   A-rows stored prescaled by log2(e) into AX .x (stride 2).
//   blocks [320,328): x transpose tiles -> AX0 .y
// ---------------------------------------------------------------------------
__global__ __launch_bounds__(256) void prep_kernel(
    const float* __restrict__ x,  const float* __restrict__ u,
    const float* __restrict__ a0w, const float* __restrict__ a0b,
    const float* __restrict__ b0w, const float* __restrict__ b0b,
    const float* __restrict__ a1w, const float* __restrict__ a1b,
    const float* __restrict__ b1w, const float* __restrict__ b1b,
    const float* __restrict__ a2w, const float* __restrict__ a2b,
    const float* __restrict__ b2w, const float* __restrict__ b2b,
    float* __restrict__ AX0, float* __restrict__ AX1, float* __restrict__ AX2,
    float* __restrict__ C0t, float* __restrict__ C1t, float* __restrict__ C2t)
{
    __shared__ float lds[64 * 65];
    const int tid = threadIdx.x;
    const int bid = blockIdx.x;

    if (bid < 320) {
        // stage u transposed: lds[k*65+b] = u[b*64+k]
        for (int e = tid; e < BB * CONDD; e += 256)
            lds[(e & 63) * 65 + (e >> 6)] = u[e];
        __syncthreads();

        const int b   = tid & 63;
        const int wid = __builtin_amdgcn_readfirstlane(tid >> 6);
        const int r0  = bid * 16 + wid * 4;          // 4 rows per wave, same segment

        const float* w; const float* bias; float* out; int stride; float scale; int lr0;
        if      (r0 <  512) { w = a0w; bias = a0b; out = AX0; stride = 2; scale = L2E; lr0 = r0;        }
        else if (r0 < 1536) { w = b0w; bias = b0b; out = C0t; stride = 1; scale = 1.f; lr0 = r0 -  512; }
        else if (r0 < 2560) { w = a1w; bias = a1b; out = AX1; stride = 2; scale = L2E; lr0 = r0 - 1536; }
        else if (r0 < 3584) { w = b1w; bias = b1b; out = C1t; stride = 1; scale = 1.f; lr0 = r0 - 2560; }
        else if (r0 < 4608) { w = a2w; bias = a2b; out = AX2; stride = 2; scale = L2E; lr0 = r0 - 3584; }
        else                { w = b2w; bias = b2b; out = C2t; stride = 1; scale = 1.f; lr0 = r0 - 4608; }

        const float* __restrict__ w0 = w + (lr0 + 0) * CONDD;
        const float* __restrict__ w1 = w + (lr0 + 1) * CONDD;
        const float* __restrict__ w2 = w + (lr0 + 2) * CONDD;
        const float* __restrict__ w3 = w + (lr0 + 3) * CONDD;
        float acc0 = bias[lr0 + 0], acc1 = bias[lr0 + 1];
        float acc2 = bias[lr0 + 2], acc3 = bias[lr0 + 3];
        #pragma unroll
        for (int k = 0; k < CONDD; ++k) {
            const float uv = lds[k * 65 + b];
            acc0 = fmaf(w0[k], uv, acc0);
            acc1 = fmaf(w1[k], uv, acc1);
            acc2 = fmaf(w2[k], uv, acc2);
            acc3 = fmaf(w3[k], uv, acc3);
        }
        out[((lr0 + 0) * 64 + b) * stride] = acc0 * scale;
        out[((lr0 + 1) * 64 + b) * stride] = acc1 * scale;
        out[((lr0 + 2) * 64 + b) * stride] = acc2 * scale;
        out[((lr0 + 3) * 64 + b) * stride] = acc3 * scale;
    } else {
        // transpose one 64(b) x 64(i) tile of x into AX0 .y slots
        const int i0 = (bid - 320) * 64;
        for (int e = tid; e < 64 * 64; e += 256) {
            int r = e >> 6, c = e & 63;                // r=b, c=i offset
            lds[c * 65 + r] = x[r * NIN + i0 + c];
        }
        __syncthreads();
        for (int e = tid; e < 64 * 64; e += 256) {
            int r = e >> 6, c = e & 63;                // r=i offset, c=b
            AX0[((i0 + r) * 64 + c) * 2 + 1] = lds[r * 65 + c];
        }
    }
}

// ---------------------------------------------------------------------------
// Branchless gated masked matvec (common body):
//   out[o,b] = sum_i 1/(1+2^(-A'[i,b]*Ct[o,b])) * m[o,i]*W[o,i] * X[i,b]
// Block: 512 threads = 8 waves; OT o's per block; waves split I 8-ways.
// m/W are wave-uniform s_load streams; AX is one coalesced dwordx2 per iter.
// ---------------------------------------------------------------------------
template<int I, int OT, bool FINAL>
__device__ __forceinline__ void gated_body(
    const float2* __restrict__ AX, const float* __restrict__ Ct,
    const float*  __restrict__ M,  const float* __restrict__ W,
    float* __restrict__ out)
{
    constexpr int ICW = I / 8;                  // i extent per wave
    const int tid = threadIdx.x;
    const int b   = tid & 63;
    const int wid = __builtin_amdgcn_readfirstlane(tid >> 6);   // 0..7 uniform
    const int o0  = blockIdx.x * OT;
    const int ibase = wid * ICW;

    float cc[OT], acc[OT];
    const float* __restrict__ mrow[OT];
    const float* __restrict__ wrow[OT];
    #pragma unroll
    for (int oo = 0; oo < OT; ++oo) {
        cc[oo]   = Ct[(o0 + oo) * 64 + b];
        mrow[oo] = M + (size_t)(o0 + oo) * I + ibase;
        wrow[oo] = W + (size_t)(o0 + oo) * I + ibase;
        acc[oo]  = 0.f;
    }
    const float2* __restrict__ axp = AX + (size_t)ibase * 64 + b;

    #pragma unroll 8
    for (int ii = 0; ii < ICW; ++ii) {
        const float2 ax = axp[(size_t)ii * 64];
        #pragma unroll
        for (int oo = 0; oo < OT; ++oo) {
            const float mw = mrow[oo][ii] * wrow[oo][ii];       // s_load * s_load
            const float t  = __builtin_amdgcn_exp2f(-(ax.x * cc[oo]));
            const float s  = __builtin_amdgcn_rcpf(1.f + t);    // inf-safe: ->0
            acc[oo] = fmaf(s, mw * ax.y, acc[oo]);
        }
    }

    __shared__ float red[8][OT][64];
    #pragma unroll
    for (int oo = 0; oo < OT; ++oo) red[wid][oo][b] = acc[oo];
    __syncthreads();
    if (tid < OT * 64) {
        const int oo = tid >> 6, bb = tid & 63;
        float v = 0.f;
        #pragma unroll
        for (int w8 = 0; w8 < 8; ++w8) v += red[w8][oo][bb];
        if (FINAL) out[bb * NOUTD + (o0 + oo)] = v;             // (B, NOUT)
        else       out[((o0 + oo) * 64 + bb) * 2 + 1] = v;      // next AX .y
    }
}

__global__ __launch_bounds__(512) void gated_l1(
    const float2* __restrict__ AX, const float* __restrict__ Ct,
    const float* __restrict__ M, const float* __restrict__ W, float* __restrict__ out)
{ gated_body<NIN, 4, false>(AX, Ct, M, W, out); }

__global__ __launch_bounds__(512) void gated_l2(
    const float2* __restrict__ AX, const float* __restrict__ Ct,
    const float* __restrict__ M, const float* __restrict__ W, float* __restrict__ out)
{ gated_body<H1D, 4, false>(AX, Ct, M, W, out); }

__global__ __launch_bounds__(512) void gated_l3(
    const float2* __restrict__ AX, const float* __restrict__ Ct,
    const float* __restrict__ M, const float* __restrict__ W, float* __restrict__ out)
{ gated_body<H2D, 2, true>(AX, Ct, M, W, out); }

// ---------------------------------------------------------------------------
extern "C" void kernel_launch(void* const* d_in, const int* in_sizes, int n_in,
                              void* d_out, int out_size, void* d_ws, size_t ws_size,
                              hipStream_t stream) {
    (void)in_sizes; (void)n_in; (void)out_size; (void)ws_size;
    const float* x   = (const float*)d_in[0];
    const float* u   = (const float*)d_in[1];
    const float* m0  = (const float*)d_in[2];
    const float* m1  = (const float*)d_in[3];
    const float* m2  = (const float*)d_in[4];
    const float* W0  = (const float*)d_in[5];
    const float* W1  = (const float*)d_in[6];
    const float* W2  = (const float*)d_in[7];
    const float* a0w = (const float*)d_in[8];  const float* a0b = (const float*)d_in[9];
    const float* b0w = (const float*)d_in[10]; const float* b0b = (const float*)d_in[11];
    const float* a1w = (const float*)d_in[12]; const float* a1b = (const float*)d_in[13];
    const float* b1w = (const float*)d_in[14]; const float* b1b = (const float*)d_in[15];
    const float* a2w = (const float*)d_in[16]; const float* a2b = (const float*)d_in[17];
    const float* b2w = (const float*)d_in[18]; const float* b2b = (const float*)d_in[19];

    float* ws  = (float*)d_ws;                 // offsets in floats
    float* AX0 = ws;                           // float2[512*64]   = 65536
    float* AX1 = ws + 65536;                   // float2[1024*64]  = 131072
    float* AX2 = ws + 196608;                  // float2[1024*64]  = 131072
    float* C0t = ws + 327680;                  // 1024*64 = 65536
    float* C1t = ws + 393216;                  // 1024*64 = 65536
    float* C2t = ws + 458752;                  // 512*64  = 32768
    float* out = (float*)d_out;

    prep_kernel<<<328, 256, 0, stream>>>(x, u,
        a0w, a0b, b0w, b0b, a1w, a1b, b1w, b1b, a2w, a2b, b2w, b2b,
        AX0, AX1, AX2, C0t, C1t, C2t);

    // L1: I=512,  O=1024, OT=4 -> 256 blocks; writes AX1 .y
    gated_l1<<<H1D / 4,   512, 0, stream>>>((const float2*)AX0, C0t, m0, W0, AX1);
    // L2: I=1024, O=1024, OT=4 -> 256 blocks; writes AX2 .y
    gated_l2<<<H2D / 4,   512, 0, stream>>>((const float2*)AX1, C1t, m1, W1, AX2);
    // L3: I=1024, O=512,  OT=2 -> 256 blocks; writes d_out (B, NOUT)
    gated_l3<<<NOUTD / 2, 512, 0, stream>>>((const float2*)AX2, C2t, m2, W2, out);
}